// Round 2
// baseline (580.733 us; speedup 1.0000x reference)
//
#include <hip/hip_runtime.h>
#include <hip/hip_bf16.h>

// Problem constants (from reference): V=128000, D=512, B=2, T=1024, K=512
#define V_SZ 128000
#define D_SZ 512
#define N_ROWS 2048
#define K_SZ 512
#define KM1 511

__global__ void zero_out_kernel(float* out) { out[0] = 0.0f; }

__global__ __launch_bounds__(256) void sampled_softmax_loss_kernel(
    const float* __restrict__ H,      // [N, D]
    const int*   __restrict__ labels, // [N]
    const float* __restrict__ W,      // [V, D]
    const float* __restrict__ q,      // [V]
    const int*   __restrict__ neg,    // [N, K-1]
    float* __restrict__ out)
{
    const int n   = blockIdx.x;
    const int tid = threadIdx.x;
    const int sub = tid & 15;   // lane within 16-lane candidate group
    const int grp = tid >> 4;   // 16 groups per 256-thread block

    __shared__ int   cidx[K_SZ];
    __shared__ float logits[K_SZ];
    __shared__ float red[4];

    // Stage candidate indices: [label, neg[0..510]]
    for (int i = tid; i < K_SZ; i += 256) {
        cidx[i] = (i == 0) ? labels[n] : neg[(size_t)n * KM1 + (i - 1)];
    }

    // Preload this lane's H chunks into registers: floats sub*4 + ch*64 .. +3
    float4 h[8];
    const float4* Hrow = reinterpret_cast<const float4*>(H + (size_t)n * D_SZ);
    #pragma unroll
    for (int ch = 0; ch < 8; ++ch) h[ch] = Hrow[sub + ch * 16];

    __syncthreads();

    // Each 16-lane group processes candidates grp, grp+16, ... (32 iters)
    for (int base = grp; base < K_SZ; base += 16) {
        const int c = cidx[base];
        const float4* Wrow = reinterpret_cast<const float4*>(W + (size_t)c * D_SZ);
        float4 acc = make_float4(0.f, 0.f, 0.f, 0.f);
        #pragma unroll
        for (int ch = 0; ch < 8; ++ch) {
            float4 w = Wrow[sub + ch * 16];
            acc.x = fmaf(w.x, h[ch].x, acc.x);
            acc.y = fmaf(w.y, h[ch].y, acc.y);
            acc.z = fmaf(w.z, h[ch].z, acc.z);
            acc.w = fmaf(w.w, h[ch].w, acc.w);
        }
        float s = (acc.x + acc.y) + (acc.z + acc.w);
        // reduce across the 16-lane group (lanes are contiguous, xor stays inside)
        s += __shfl_xor(s, 1);
        s += __shfl_xor(s, 2);
        s += __shfl_xor(s, 4);
        s += __shfl_xor(s, 8);
        if (sub == 0) logits[base] = s;
    }
    __syncthreads();

    // --- logsumexp over logits[0..511] ---
    const int wave = tid >> 6;
    float m = -INFINITY;
    for (int i = tid; i < K_SZ; i += 256) m = fmaxf(m, logits[i]);
    #pragma unroll
    for (int off = 32; off > 0; off >>= 1) m = fmaxf(m, __shfl_xor(m, off));
    if ((tid & 63) == 0) red[wave] = m;
    __syncthreads();
    m = fmaxf(fmaxf(red[0], red[1]), fmaxf(red[2], red[3]));
    __syncthreads();  // everyone has m before red is reused

    float s = 0.f;
    for (int i = tid; i < K_SZ; i += 256) s += expf(logits[i] - m);
    #pragma unroll
    for (int off = 32; off > 0; off >>= 1) s += __shfl_xor(s, off);
    if ((tid & 63) == 0) red[wave] = s;
    __syncthreads();

    if (tid == 0) {
        float tot = red[0] + red[1] + red[2] + red[3];
        float lse = m + logf(tot);
        float q0  = fmaxf(q[cidx[0]], 1e-10f);
        float loss = -logits[0] + lse + logf(q0);
        atomicAdd(out, loss * (1.0f / N_ROWS));
    }
}

extern "C" void kernel_launch(void* const* d_in, const int* in_sizes, int n_in,
                              void* d_out, int out_size, void* d_ws, size_t ws_size,
                              hipStream_t stream) {
    const float* H      = (const float*)d_in[0];  // hidden_states [B,T,D]
    const int*   labels = (const int*)  d_in[1];  // [B,T]
    const float* W      = (const float*)d_in[2];  // weight [V,D]
    const float* q      = (const float*)d_in[3];  // sampling_probs [V]
    const int*   neg    = (const int*)  d_in[4];  // neg_samples [N, K-1]
    float* out = (float*)d_out;

    zero_out_kernel<<<1, 1, 0, stream>>>(out);
    sampled_softmax_loss_kernel<<<N_ROWS, 256, 0, stream>>>(H, labels, W, q, neg, out);
}